// Round 7
// baseline (240.915 us; speedup 1.0000x reference)
//
#include <hip/hip_runtime.h>
#include <hip/hip_bf16.h>

// TriangleAttentionStartingNode  B=1, N=256, C_Z=128, H=4, D=32, TOTAL=128
// Round 7: fused attention with 2 blocks/CU overlap.
//   prep:   pack W^T (Q pre-scaled) + Wo^T into MFMA-frag-order bf16
//   lnbias: LN fp32 -> xn bf16 [65536][128] + bias fp32 in attn-frag order
//   fused:  512 blocks x 512 thr: block = (i, query-half). K/V projected for
//           all 256 keys into frag-order LDS; Q/P via per-wave LDS round-trip
//           (no bpermute); bias preloaded in MFMA acc; oproj fused, stores
//           reordered r-outer/ct-inner to kill write amplification.

#define QSCALE 0.17677669529663687f  // 1/sqrt(32)

typedef __attribute__((ext_vector_type(8))) short bf16x8;
typedef __attribute__((ext_vector_type(4))) float f32x4;

__device__ __forceinline__ ushort f2bf(float f) {
    uint32_t u = __builtin_bit_cast(uint32_t, f);
    uint32_t r = (u + 0x7FFFu + ((u >> 16) & 1u)) >> 16;  // RNE
    return (ushort)r;
}
__device__ __forceinline__ uint pk2(float a, float b) {   // v_cvt_pk_bf16_f32
    union { __hip_bfloat162 h; uint u; } cv;
    cv.h = __float22bfloat162_rn(make_float2(a, b));
    return cv.u;
}
__device__ __forceinline__ float4 ld4f(const float* p) { return *(const float4*)p; }

// ---------------------------------------------------------------------------
// prep: Wfrag[ct 0..31][ks][lane][e]: n = ct*16+(lane&15), k = ks*32+(lane>>4)*8+e
//   n: 0..127 Wq*QSCALE, 128..255 Wk, 256..383 Wv, 384..511 Wg.
// WoFrag: 8 ct over Wo^T.  grid 320*256 = 65536 + 16384.
// ---------------------------------------------------------------------------
__global__ __launch_bounds__(256) void prep_kernel(
    const float* __restrict__ Wq, const float* __restrict__ Wk, const float* __restrict__ Wv,
    const float* __restrict__ Wg, const float* __restrict__ Wo,
    ushort* __restrict__ Wfrag, ushort* __restrict__ WoFrag)
{
    int idx = blockIdx.x * 256 + threadIdx.x;
    if (idx < 65536) {
        int e = idx & 7, lane = (idx >> 3) & 63, ks = (idx >> 9) & 3, ct = idx >> 11;
        int n = ct * 16 + (lane & 15);
        int k = ks * 32 + (lane >> 4) * 8 + e;
        float v;
        if (n < 128)      v = Wq[k * 128 + n] * QSCALE;
        else if (n < 256) v = Wk[k * 128 + (n - 128)];
        else if (n < 384) v = Wv[k * 128 + (n - 256)];
        else              v = Wg[k * 128 + (n - 384)];
        Wfrag[idx] = f2bf(v);
    } else {
        int idx2 = idx - 65536;
        int e = idx2 & 7, lane = (idx2 >> 3) & 63, ks = (idx2 >> 9) & 3, ct = idx2 >> 11;
        int n = ct * 16 + (lane & 15);
        int k = ks * 32 + (lane >> 4) * 8 + e;
        WoFrag[idx2] = f2bf(Wo[k * 128 + n]);
    }
}

// ---------------------------------------------------------------------------
// lnbias: per x-row p=(j,k): LN fp32 -> xn bf16 row-major; dot with Wb ->
// 4 fp32 bias, scattered into attn-frag order:
// BbF[h*65536 + ((j>>4)*16 + (k>>4))*256 + ((k&15)>>2)*64 + (j&15)*4 + (k&3)].
// 512 blocks x 256 thr, 2 threads/row.
// ---------------------------------------------------------------------------
__global__ __launch_bounds__(256) void lnbias_kernel(
    const float* __restrict__ x, const float* __restrict__ gamma,
    const float* __restrict__ beta, const float* __restrict__ Wb,
    ushort* __restrict__ xn, float* __restrict__ BbF)
{
    const int t = threadIdx.x;
    const int p = blockIdx.x * 128 + (t >> 1);
    const int half = t & 1;
    const float* rp = x + p * 128 + half * 64;
    float4 v[16];
    float sum = 0.f, ssq = 0.f;
#pragma unroll
    for (int ii = 0; ii < 16; ++ii) {
        v[ii] = ld4f(rp + ii * 4);
        sum += v[ii].x + v[ii].y + v[ii].z + v[ii].w;
        ssq += v[ii].x * v[ii].x + v[ii].y * v[ii].y + v[ii].z * v[ii].z + v[ii].w * v[ii].w;
    }
    sum += __shfl_xor(sum, 1);
    ssq += __shfl_xor(ssq, 1);
    float mu = sum * (1.f / 128.f);
    float var = ssq * (1.f / 128.f) - mu * mu;
    float rstd = rsqrtf(var + 1e-5f);

    float d0 = 0.f, d1 = 0.f, d2 = 0.f, d3 = 0.f;
    uint2* xp = (uint2*)(xn + p * 128 + half * 64);
#pragma unroll
    for (int ii = 0; ii < 16; ++ii) {
        int c = half * 64 + ii * 4;
        float4 g4 = ld4f(gamma + c), b4 = ld4f(beta + c);
        float n0 = (v[ii].x - mu) * rstd * g4.x + b4.x;
        float n1 = (v[ii].y - mu) * rstd * g4.y + b4.y;
        float n2 = (v[ii].z - mu) * rstd * g4.z + b4.z;
        float n3 = (v[ii].w - mu) * rstd * g4.w + b4.w;
        uint2 u; u.x = pk2(n0, n1); u.y = pk2(n2, n3);
        xp[ii] = u;
        float4 w0 = ld4f(Wb + (c + 0) * 4);
        float4 w1 = ld4f(Wb + (c + 1) * 4);
        float4 w2 = ld4f(Wb + (c + 2) * 4);
        float4 w3 = ld4f(Wb + (c + 3) * 4);
        d0 += n0 * w0.x + n1 * w1.x + n2 * w2.x + n3 * w3.x;
        d1 += n0 * w0.y + n1 * w1.y + n2 * w2.y + n3 * w3.y;
        d2 += n0 * w0.z + n1 * w1.z + n2 * w2.z + n3 * w3.z;
        d3 += n0 * w0.w + n1 * w1.w + n2 * w2.w + n3 * w3.w;
    }
    d0 += __shfl_xor(d0, 1);
    d1 += __shfl_xor(d1, 1);
    d2 += __shfl_xor(d2, 1);
    d3 += __shfl_xor(d3, 1);
    if (half == 0) {
        int j = p >> 8, k = p & 255;
        int base = ((j >> 4) * 16 + (k >> 4)) * 256 + ((k & 15) >> 2) * 64 + (j & 15) * 4 + (k & 3);
        BbF[base]          = d0;
        BbF[base + 65536]  = d1;
        BbF[base + 131072] = d2;
        BbF[base + 196608] = d3;
    }
}

// ---------------------------------------------------------------------------
// fused: grid 512 = (i, jh); 512 thr = 8 waves. Wave w owns queries
// j = jh*128 + w*16 + (lane&15) and stages K/V for key rows {w*16+m} and
// {128+w*16+m}. Per h: project K/V -> frag-order LDS, Q -> per-wave LDS
// round-trip -> B-frag, G -> regs; barrier; 16q x 256k attention with bias
// in acc, P via per-wave LDS; barrier. Epilogue: gvals -> aliased LDS,
// fused oproj with write-amp-free store order.
// LDS: K 16KB | V 16KB | Pl 18KB = 50KB -> 2 blocks/CU (grid = 2/CU).
// ---------------------------------------------------------------------------
__global__ __launch_bounds__(512, 4) void fused_kernel(
    const ushort* __restrict__ xn, const ushort* __restrict__ Wfrag,
    const float* __restrict__ bg, const float* __restrict__ BbF,
    const ushort* __restrict__ WoFrag, const float* __restrict__ bo,
    float* __restrict__ out)
{
    __shared__ ushort smem[25600];       // 51.2 KB
    ushort* K_s = smem;                  // [16 tiles][64][8]
    ushort* V_s = smem + 8192;           // [8 kcg][2 dt][64][8]
    ushort* Pl  = smem + 16384;          // per-wave [16 j][72]
    ushort* GV_s = smem;                 // 16384 elems, aliases K/V after last barrier

    const int t = threadIdx.x;
    const int w = t >> 6, lane = t & 63, m = lane & 15, quad = lane >> 4;
    const int i = blockIdx.x >> 1, jh = blockIdx.x & 1;
    ushort* Plw = Pl + w * 1152;

    // ---- load xn frags for the wave's two key row-groups ----
    bf16x8 xg[2][4];
#pragma unroll
    for (int g = 0; g < 2; ++g) {
        const ushort* xr = xn + (i * 256 + g * 128 + w * 16 + m) * 128 + quad * 8;
#pragma unroll
        for (int ks = 0; ks < 4; ++ks)
            xg[g][ks] = *(const bf16x8*)(xr + ks * 32);
    }

    uint gst[4][4];
    const int jtg = jh * 8 + w;

#pragma unroll
    for (int h = 0; h < 4; ++h) {
        // ---- K proj (both groups): D[d][k] -> K_s frag order ----
#pragma unroll
        for (int g = 0; g < 2; ++g) {
#pragma unroll
            for (int dt = 0; dt < 2; ++dt) {
                const int ct = 8 + 2 * h + dt;
                f32x4 acc = (f32x4){0.f, 0.f, 0.f, 0.f};
#pragma unroll
                for (int ks = 0; ks < 4; ++ks) {
                    bf16x8 wf = *(const bf16x8*)(Wfrag + ((ct * 4 + ks) * 64 + lane) * 8);
                    acc = __builtin_amdgcn_mfma_f32_16x16x32_bf16(wf, xg[g][ks], acc, 0, 0, 0);
                }
                uint2 u; u.x = pk2(acc[0], acc[1]); u.y = pk2(acc[2], acc[3]);
                *(uint2*)(K_s + (g * 8 + w) * 512 +
                          ((dt * 2 + (quad >> 1)) * 16 + m) * 8 + (quad & 1) * 4) = u;
            }
            // ---- V proj: D[k][d] -> V_s frag order ----
#pragma unroll
            for (int dt = 0; dt < 2; ++dt) {
                const int ct = 16 + 2 * h + dt;
                f32x4 acc = (f32x4){0.f, 0.f, 0.f, 0.f};
#pragma unroll
                for (int ks = 0; ks < 4; ++ks) {
                    bf16x8 wf = *(const bf16x8*)(Wfrag + ((ct * 4 + ks) * 64 + lane) * 8);
                    acc = __builtin_amdgcn_mfma_f32_16x16x32_bf16(xg[g][ks], wf, acc, 0, 0, 0);
                }
                const int kcg = g * 4 + (w >> 1);
                uint2 u; u.x = pk2(acc[0], acc[1]); u.y = pk2(acc[2], acc[3]);
                *(uint2*)(V_s + (kcg * 2 + dt) * 512 +
                          (((w & 1) * 2 + (quad >> 1)) * 16 + m) * 8 + (quad & 1) * 4) = u;
            }
        }
        // ---- Q proj (query group) -> per-wave LDS round-trip -> B-frag ----
#pragma unroll
        for (int dt = 0; dt < 2; ++dt) {
            const int ct = 2 * h + dt;
            f32x4 acc = (f32x4){0.f, 0.f, 0.f, 0.f};
#pragma unroll
            for (int ks = 0; ks < 4; ++ks) {
                bf16x8 wf = *(const bf16x8*)(Wfrag + ((ct * 4 + ks) * 64 + lane) * 8);
                acc = __builtin_amdgcn_mfma_f32_16x16x32_bf16(wf, xg[jh][ks], acc, 0, 0, 0);
            }
            uint2 u; u.x = pk2(acc[0], acc[1]); u.y = pk2(acc[2], acc[3]);
            *(uint2*)(Plw + m * 72 + dt * 16 + quad * 4) = u;
        }
        bf16x8 qf = *(const bf16x8*)(Plw + m * 72 + quad * 8);
        // ---- G proj (query group): sigmoid, C-layout regs ----
        f32x4 Gs[2];
#pragma unroll
        for (int dt = 0; dt < 2; ++dt) {
            const int ct = 24 + 2 * h + dt;
            f32x4 acc = (f32x4){0.f, 0.f, 0.f, 0.f};
#pragma unroll
            for (int ks = 0; ks < 4; ++ks) {
                bf16x8 wf = *(const bf16x8*)(Wfrag + ((ct * 4 + ks) * 64 + lane) * 8);
                acc = __builtin_amdgcn_mfma_f32_16x16x32_bf16(wf, xg[jh][ks], acc, 0, 0, 0);
            }
            float4 bg4 = ld4f(bg + h * 32 + dt * 16 + quad * 4);
            Gs[dt][0] = 1.f / (1.f + __expf(-(acc[0] + bg4.x)));
            Gs[dt][1] = 1.f / (1.f + __expf(-(acc[1] + bg4.y)));
            Gs[dt][2] = 1.f / (1.f + __expf(-(acc[2] + bg4.z)));
            Gs[dt][3] = 1.f / (1.f + __expf(-(acc[3] + bg4.w)));
        }

        __syncthreads();   // K/V visible to all waves

        // ---- attention: 16 queries x 256 keys, bias in acc ----
        f32x4 O0 = (f32x4){0.f, 0.f, 0.f, 0.f};
        f32x4 O1 = (f32x4){0.f, 0.f, 0.f, 0.f};
        float lsum = 0.f;
        const float* bb = BbF + ((h * 16 + jtg) * 16) * 256 + lane * 4;
#pragma unroll
        for (int kt2 = 0; kt2 < 4; ++kt2) {
#pragma unroll
            for (int kk = 0; kk < 4; ++kk) {
                const int tile = kt2 * 4 + kk;
                bf16x8 kf = *(const bf16x8*)(K_s + tile * 512 + lane * 8);
                f32x4 bias = *(const f32x4*)(bb + tile * 256);
                f32x4 S = __builtin_amdgcn_mfma_f32_16x16x32_bf16(kf, qf, bias, 0, 0, 0);
                float p0 = __expf(S[0]), p1 = __expf(S[1]);
                float p2 = __expf(S[2]), p3 = __expf(S[3]);
                lsum += p0 + p1 + p2 + p3;
                uint2 u; u.x = pk2(p0, p1); u.y = pk2(p2, p3);
                *(uint2*)(Plw + m * 72 + kk * 16 + quad * 4) = u;
            }
#pragma unroll
            for (int kc = 0; kc < 2; ++kc) {
                bf16x8 pf = *(const bf16x8*)(Plw + m * 72 + kc * 32 + quad * 8);
                const int kcg = kt2 * 2 + kc;
                bf16x8 vf0 = *(const bf16x8*)(V_s + (kcg * 2 + 0) * 512 + lane * 8);
                bf16x8 vf1 = *(const bf16x8*)(V_s + (kcg * 2 + 1) * 512 + lane * 8);
                O0 = __builtin_amdgcn_mfma_f32_16x16x32_bf16(vf0, pf, O0, 0, 0, 0);
                O1 = __builtin_amdgcn_mfma_f32_16x16x32_bf16(vf1, pf, O1, 0, 0, 0);
            }
        }
        lsum += __shfl_xor(lsum, 16);
        lsum += __shfl_xor(lsum, 32);
        const float rl = 1.f / lsum;
        gst[h][0] = pk2(O0[0] * rl * Gs[0][0], O0[1] * rl * Gs[0][1]);
        gst[h][1] = pk2(O0[2] * rl * Gs[0][2], O0[3] * rl * Gs[0][3]);
        gst[h][2] = pk2(O1[0] * rl * Gs[1][0], O1[1] * rl * Gs[1][1]);
        gst[h][3] = pk2(O1[2] * rl * Gs[1][2], O1[3] * rl * Gs[1][3]);

        __syncthreads();   // all K/V reads done before next h (or GV) overwrites
    }

    // ---- gvals (C-layout [d][j] per h,dt) -> own-wave frag-order GV_s ----
#pragma unroll
    for (int h = 0; h < 4; ++h) {
#pragma unroll
        for (int dt = 0; dt < 2; ++dt) {
            uint2 u; u.x = gst[h][dt * 2]; u.y = gst[h][dt * 2 + 1];
            *(uint2*)(GV_s + w * 2048 +
                      (h * 64 + (dt * 2 + (quad >> 1)) * 16 + m) * 8 + (quad & 1) * 4) = u;
        }
    }
    // own-region write->read within the wave; no barrier needed

    // ---- oproj: acc all 8 ct, then store r-outer/ct-inner (full rows) ----
    bf16x8 gf[4];
#pragma unroll
    for (int ks = 0; ks < 4; ++ks)
        gf[ks] = *(const bf16x8*)(GV_s + w * 2048 + (ks * 64 + lane) * 8);

    float bov[8];
#pragma unroll
    for (int ct = 0; ct < 8; ++ct) bov[ct] = bo[ct * 16 + m];

    f32x4 acc8[8];
#pragma unroll
    for (int ct = 0; ct < 8; ++ct) {
        f32x4 acc = (f32x4){0.f, 0.f, 0.f, 0.f};
#pragma unroll
        for (int ks = 0; ks < 4; ++ks) {
            bf16x8 wf = *(const bf16x8*)(WoFrag + ((ct * 4 + ks) * 64 + lane) * 8);
            acc = __builtin_amdgcn_mfma_f32_16x16x32_bf16(gf[ks], wf, acc, 0, 0, 0);
        }
        acc8[ct] = acc;
    }
#pragma unroll
    for (int rr = 0; rr < 4; ++rr) {
        float* orow = out + (i * 256 + jh * 128 + w * 16 + quad * 4 + rr) * 128;
#pragma unroll
        for (int ct = 0; ct < 8; ++ct)
            orow[ct * 16 + m] = acc8[ct][rr] + bov[ct];
    }
}

// ---------------------------------------------------------------------------
extern "C" void kernel_launch(void* const* d_in, const int* in_sizes, int n_in,
                              void* d_out, int out_size, void* d_ws, size_t ws_size,
                              hipStream_t stream) {
    const float* x     = (const float*)d_in[0];
    const float* gamma = (const float*)d_in[1];
    const float* beta  = (const float*)d_in[2];
    const float* Wq    = (const float*)d_in[3];
    const float* Wk    = (const float*)d_in[4];
    const float* Wv    = (const float*)d_in[5];
    const float* Wb    = (const float*)d_in[6];
    const float* Wg    = (const float*)d_in[7];
    const float* bg    = (const float*)d_in[8];
    const float* Wo    = (const float*)d_in[9];
    const float* bo    = (const float*)d_in[10];

    ushort* Wfrag  = (ushort*)d_ws;            // 65536 elems
    ushort* WoFrag = Wfrag + 65536;            // 16384 elems
    ushort* xn     = WoFrag + 16384;           // 8388608 elems (16.8 MB)
    float*  BbF    = (float*)(xn + 8388608);   // 262144 fp32 (1 MB)

    prep_kernel<<<320, 256, 0, stream>>>(Wq, Wk, Wv, Wg, Wo, Wfrag, WoFrag);
    lnbias_kernel<<<512, 256, 0, stream>>>(x, gamma, beta, Wb, xn, BbF);
    fused_kernel<<<512, 512, 0, stream>>>(xn, Wfrag, bg, BbF, WoFrag, bo, (float*)d_out);
}